// Round 7
// baseline (197.745 us; speedup 1.0000x reference)
//
#include <hip/hip_runtime.h>
#include <hip/hip_bf16.h>
#include <stdint.h>

#define S_LEN 1024
#define HDIM  1024
#define NHEADS 16
#define HEAD_D 64
#define KSEL  512
#define BATCH 8

typedef unsigned short ushort_t;
typedef __attribute__((ext_vector_type(8))) __bf16 bf16x8;
typedef __attribute__((ext_vector_type(4))) float  f32x4;
typedef __attribute__((ext_vector_type(16))) float f32x16;

typedef const __attribute__((address_space(1))) void cg_void;
typedef __attribute__((address_space(3))) void lds_void;

__device__ __forceinline__ void gl_lds16(const void* g, void* l) {
    __builtin_amdgcn_global_load_lds((cg_void*)g, (lds_void*)l, 16, 0, 0);
}

// round-to-nearest-even f32 -> bf16 (finite inputs only)
__device__ __forceinline__ ushort_t f2bf(float f) {
    union { float f; unsigned int i; } x; x.f = f;
    unsigned int r = (x.i + 0x7fffu + ((x.i >> 16) & 1u)) >> 16;
    return (ushort_t)r;
}

#define BAR() __asm__ volatile("s_barrier" ::: "memory")
#define VMCNT(n) __asm__ volatile("s_waitcnt vmcnt(" #n ")" ::: "memory")
#define LGKM0() __asm__ volatile("s_waitcnt lgkmcnt(0)" ::: "memory")

// ---------------- kernel 0: prep = cvt(hidden,Wq,Wk,Wv) + compact -----------
__global__ __launch_bounds__(1024) void prep_kernel(
    const float* __restrict__ hidden, const float* __restrict__ wq,
    const float* __restrict__ wk, const float* __restrict__ wv,
    const int* __restrict__ remain,
    ushort_t* __restrict__ hbf, ushort_t* __restrict__ wqb,
    ushort_t* __restrict__ wkb, ushort_t* __restrict__ wvb,
    int* __restrict__ idx, int* __restrict__ valid) {
    __shared__ int wsum[16];
    __shared__ int woff[17];
    int blk = blockIdx.x;
    if (blk < 2816) {
        const float* s; ushort_t* d; int base;
        if (blk < 2048)      { s = hidden; d = hbf; base = blk; }
        else if (blk < 2304) { s = wq; d = wqb; base = blk - 2048; }
        else if (blk < 2560) { s = wk; d = wkb; base = blk - 2304; }
        else                 { s = wv; d = wvb; base = blk - 2560; }
        int i = base * 1024 + threadIdx.x;
        float4 v = ((const float4*)s)[i];
        ushort4 o;
        o.x = f2bf(v.x); o.y = f2bf(v.y); o.z = f2bf(v.z); o.w = f2bf(v.w);
        ((ushort4*)d)[i] = o;
    } else {
        int b = blk - 2816, t = threadIdx.x;
        int r = remain[b * S_LEN + t];
        unsigned long long m = __ballot(r != 0);
        int lane = t & 63, w = t >> 6;
        int pre = __popcll(m & ((1ull << lane) - 1ull));
        if (lane == 0) wsum[w] = __popcll(m);
        __syncthreads();
        if (t == 0) { int a = 0; for (int i = 0; i < 16; i++) { woff[i] = a; a += wsum[i]; } woff[16] = a; }
        __syncthreads();
        int tot = woff[16];
        int onesBefore = woff[w] + pre;
        int slot = r ? onesBefore : (tot + (t - onesBefore));
        if (slot < KSEL) { idx[b * KSEL + slot] = t; valid[b * KSEL + slot] = r; }
    }
}

// ---------------- kernel 1a/1b: projection GEMM, SPLIT for diagnosis --------
// R7: the R6 fused gemm (60.0us verified) split into Q (256 blk) + 2x KV
// (512 blk each) so the rocprof top-5 table can surface attn/prep durations
// (total-minus-gemm has been 127.0+-0.3us for six rounds with attn/prep
// never observed).  Same tile structure / swizzles / epilogues as R6.
#define QSCALE 0.1803368801111244f
#define LT_PITCH 136

__global__ __launch_bounds__(256, 4) void gemm_kv(
    const ushort_t* __restrict__ hbf, const ushort_t* __restrict__ wkv,
    const float* __restrict__ bk, const float* __restrict__ bv,
    ushort_t* __restrict__ kp, ushort_t* __restrict__ vt, int noff) {
    __shared__ __align__(16) ushort_t pool[16384];
    ushort_t* As = pool;
    ushort_t* Bs = pool + 8192;
    const int ii = blockIdx.x + noff;
    const int x = ii & 7, j = ii >> 3;
    const int bmI = x * 8 + (j & 7);          // m fastest per XCD (R6 verified)
    const int bnI = j >> 3;
    const long bm = (long)bmI * 128;
    const int bn = bnI * 128;

    const int tid = threadIdx.x;
    const int lane = tid & 63;
    const int w = tid >> 6;
    const int quad = lane >> 4;
    const int cl = lane & 15;
    const int srow = w * 16 + (lane >> 2);
    const int fs = ((lane >> 2) & 3) ^ ((lane >> 4) & 3);
    const int scol = ((lane & 3) ^ fs) * 8;
    const int lds_off = w * 512 + lane * 8;
    const int wr = (w >> 1) * 64, wc = (w & 1) * 64;
    const int fr = (cl & 3) ^ ((cl >> 2) & 3);
    const int qo = (quad ^ fr) * 8;

    f32x4 acc[4][4] = {};

    for (int k0 = 0; k0 < HDIM; k0 += 64) {
#pragma unroll
        for (int p = 0; p < 2; p++)
#pragma unroll
            for (int hh = 0; hh < 2; hh++) {
                gl_lds16(hbf + (bm + p * 64 + srow) * HDIM + k0 + hh * 32 + scol,
                         &As[hh * 4096 + p * 2048 + lds_off]);
                gl_lds16(wkv + ((long)(bn + p * 64 + srow)) * HDIM + k0 + hh * 32 + scol,
                         &Bs[hh * 4096 + p * 2048 + lds_off]);
            }
        __syncthreads();
#pragma unroll
        for (int hh = 0; hh < 2; hh++) {
            bf16x8 af[4], bfr[4];
#pragma unroll
            for (int mt = 0; mt < 4; mt++)
                af[mt] = *(const bf16x8*)&As[hh * 4096 + (wr + mt * 16 + cl) * 32 + qo];
#pragma unroll
            for (int nt = 0; nt < 4; nt++)
                bfr[nt] = *(const bf16x8*)&Bs[hh * 4096 + (wc + nt * 16 + cl) * 32 + qo];
#pragma unroll
            for (int mt = 0; mt < 4; mt++)
#pragma unroll
                for (int nt = 0; nt < 4; nt++)
                    acc[mt][nt] = __builtin_amdgcn_mfma_f32_16x16x32_bf16(af[mt], bfr[nt], acc[mt][nt], 0, 0, 0);
        }
        __syncthreads();
    }

    if (bn < 1024) {
#pragma unroll
        for (int nt = 0; nt < 4; nt++) {
            int col = bn + wc + nt * 16 + cl;
            float bvk = bk[col];
#pragma unroll
            for (int mt = 0; mt < 4; mt++) {
                long row = bm + wr + mt * 16 + quad * 4;
#pragma unroll
                for (int r = 0; r < 4; r++)
                    kp[(row + r) * HDIM + col] = f2bf(acc[mt][nt][r] + bvk);
            }
        }
    } else {
        ushort_t* Lt = pool;
        long b_ = bm >> 10, s0 = bm & 1023;
#pragma unroll
        for (int p2 = 0; p2 < 2; p2++) {
            if ((w & 1) == p2) {
#pragma unroll
                for (int nt = 0; nt < 4; nt++) {
                    int cloc = nt * 16 + cl;
                    float bvv = bv[bn - 1024 + p2 * 64 + cloc];
#pragma unroll
                    for (int mt = 0; mt < 4; mt++) {
                        int row0 = wr + mt * 16 + quad * 4;
#pragma unroll
                        for (int r = 0; r < 4; r++)
                            Lt[cloc * LT_PITCH + row0 + r] = f2bf(acc[mt][nt][r] + bvv);
                    }
                }
            }
            __syncthreads();
            int c2 = tid >> 2, quarter = tid & 3;
            long gbase = ((b_ << 10) + (bn - 1024) + p2 * 64 + c2) * 1024 + s0 + quarter * 32;
            const ushort_t* src = Lt + c2 * LT_PITCH + quarter * 32;
#pragma unroll
            for (int q8 = 0; q8 < 4; q8++)
                *(bf16x8*)(vt + gbase + q8 * 8) = *(const bf16x8*)(src + q8 * 8);
            __syncthreads();
        }
    }
}

__global__ __launch_bounds__(256, 4) void gemm_q(
    const ushort_t* __restrict__ hbf, const ushort_t* __restrict__ wq,
    const float* __restrict__ bq,
    const int* __restrict__ idx, const int* __restrict__ valid,
    ushort_t* __restrict__ qp) {
    __shared__ __align__(16) ushort_t pool[16384];
    ushort_t* As = pool;
    ushort_t* Bs = pool + 8192;
    const int i = blockIdx.x;
    const int bmI = i >> 3, bnI = i & 7;
    const long bm = (long)bmI * 128;
    const int bn = bnI * 128;

    const int tid = threadIdx.x;
    const int lane = tid & 63;
    const int w = tid >> 6;
    const int quad = lane >> 4;
    const int cl = lane & 15;
    const int srow = w * 16 + (lane >> 2);
    const int fs = ((lane >> 2) & 3) ^ ((lane >> 4) & 3);
    const int scol = ((lane & 3) ^ fs) * 8;
    const int lds_off = w * 512 + lane * 8;
    const int wr = (w >> 1) * 64, wc = (w & 1) * 64;
    const int fr = (cl & 3) ^ ((cl >> 2) & 3);
    const int qo = (quad ^ fr) * 8;

    long ab[2];
#pragma unroll
    for (int p = 0; p < 2; p++) {
        long gr = bm + p * 64 + srow;
        int b_ = (int)(gr >> 9);
        int src = idx[(b_ << 9) + ((int)gr & 511)];
        ab[p] = ((long)(b_ << 10) + src) * HDIM;
    }

    f32x4 acc[4][4] = {};

    for (int k0 = 0; k0 < HDIM; k0 += 64) {
#pragma unroll
        for (int p = 0; p < 2; p++)
#pragma unroll
            for (int hh = 0; hh < 2; hh++) {
                gl_lds16(hbf + ab[p] + k0 + hh * 32 + scol, &As[hh * 4096 + p * 2048 + lds_off]);
                gl_lds16(wq + ((long)(bn + p * 64 + srow)) * HDIM + k0 + hh * 32 + scol,
                         &Bs[hh * 4096 + p * 2048 + lds_off]);
            }
        __syncthreads();
#pragma unroll
        for (int hh = 0; hh < 2; hh++) {
            bf16x8 af[4], bfr[4];
#pragma unroll
            for (int mt = 0; mt < 4; mt++)
                af[mt] = *(const bf16x8*)&As[hh * 4096 + (wr + mt * 16 + cl) * 32 + qo];
#pragma unroll
            for (int nt = 0; nt < 4; nt++)
                bfr[nt] = *(const bf16x8*)&Bs[hh * 4096 + (wc + nt * 16 + cl) * 32 + qo];
#pragma unroll
            for (int mt = 0; mt < 4; mt++)
#pragma unroll
                for (int nt = 0; nt < 4; nt++)
                    acc[mt][nt] = __builtin_amdgcn_mfma_f32_16x16x32_bf16(af[mt], bfr[nt], acc[mt][nt], 0, 0, 0);
        }
        __syncthreads();
    }

#pragma unroll
    for (int nt = 0; nt < 4; nt++) {
        int col = bn + wc + nt * 16 + cl;
        float bvq = bq[col];
#pragma unroll
        for (int mt = 0; mt < 4; mt++) {
            long row = bm + wr + mt * 16 + quad * 4;
#pragma unroll
            for (int r = 0; r < 4; r++) {
                float vm = (float)valid[row + r];
                qp[(row + r) * HDIM + col] = f2bf((acc[mt][nt][r] * vm + bvq) * QSCALE);
            }
        }
    }
}

// ---------------- kernel 2: flash attention, swapped-QK^T + ring-3 ----------
// R7 change: XCD-grouped flat grid.  Previously qt was the fastest grid index
// so the 4 qt-siblings sharing one (b,h)'s 256KB K/V landed on 4 DIFFERENT
// XCDs (round-robin by linear id) -> 4x HBM refetch (~128MB).  Now
// bid = slot*8 + xcd with xcd = (h+16b)&7: siblings share an XCD; each XCD's
// K/V working set = 16 (b,h) x 256KB = 4MB = its L2.  Decode:
// xcd=bid&7, slot=bid>>3, qt=slot&3, gg=xcd+8*(slot>>2), h=gg&15, b=gg>>4.
__global__ __launch_bounds__(256, 2) void attn_kernel(
    const ushort_t* __restrict__ qp, const ushort_t* __restrict__ kp,
    const ushort_t* __restrict__ vt, const float* __restrict__ mask,
    float* __restrict__ out) {
    __shared__ __align__(16) ushort_t ks[3][4096];       // [slot][s(64)][d(64)]
    __shared__ __align__(16) ushort_t vs[3][4096];       // [slot][d(64)][s(64)]
    __shared__ float mlds[1024];
    const int tid = threadIdx.x;
    const int lane = tid & 63;
    const int w = tid >> 6;          // 0..3, 32 q-rows each
    const int ql = lane & 31;
    const int hi = lane >> 5;
    const int bid = blockIdx.x;
    const int xcd = bid & 7;
    const int slot = bid >> 3;
    const int qt = slot & 3;
    const int gg = xcd + 8 * (slot >> 2);
    const int h = gg & 15;
    const int b = gg >> 4;

    const int sr2 = tid >> 3;                         // 0..31
    const int scS = ((tid & 7) ^ (sr2 & 7)) * 8;      // elems, pre-swizzled src
    const int dOf = tid * 8;                          // dest elems per half

    const long kbase = (long)b * S_LEN;
    const long vbase = (long)b * 1024 + h * HEAD_D;

    // mask -> LDS, premultiplied by log2e
    {
        float4 mv4 = *(const float4*)(mask + b * S_LEN + tid * 4);
        mlds[tid * 4 + 0] = mv4.x * 1.44269504f;
        mlds[tid * 4 + 1] = mv4.y * 1.44269504f;
        mlds[tid * 4 + 2] = mv4.z * 1.44269504f;
        mlds[tid * 4 + 3] = mv4.w * 1.44269504f;
    }

    // Q as B-fragment: lane holds q = ql, d-elems kd*16 + hi*8 + j
    const long qrow0 = (long)b * KSEL + qt * 128 + w * 32;
    bf16x8 aq[4];
#pragma unroll
    for (int kd = 0; kd < 4; kd++)
        aq[kd] = *(const bf16x8*)(qp + (qrow0 + ql) * HDIM + h * HEAD_D + kd * 16 + hi * 8);

    f32x16 O[2] = {};
    float l_loc = 0.f;

    auto stage = [&](int t, int sl) {
#pragma unroll
        for (int j = 0; j < 2; j++) {
            gl_lds16(kp + (kbase + t * 64 + j * 32 + sr2) * (long)HDIM + h * HEAD_D + scS,
                     &ks[sl][j * 2048 + dOf]);
            gl_lds16(vt + (vbase + j * 32 + sr2) * (long)S_LEN + t * 64 + scS,
                     &vs[sl][j * 2048 + dOf]);
        }
    };

    // prologue: tiles 0,1 into slots 0,1
    stage(0, 0);
    stage(1, 1);
    LGKM0();                       // publish mlds before first barrier

    int slotC = 0;                 // c % 3
    int slotP = 2;                 // (c+2) % 3
    for (int c = 0; c < S_LEN / 64; c++) {
        BAR();                     // #1: all waves done reading tile c-1
        if (c + 2 < S_LEN / 64) stage(c + 2, slotP);
        if (c < 14)       { VMCNT(8); }
        else if (c == 14) { VMCNT(4); }
        else              { VMCNT(0); }
        BAR();                     // #2: stage(c) visible block-wide
        const ushort_t* kb_ = ks[slotC];
        const ushort_t* vb_ = vs[slotC];

        // QK^T (swapped): sc[mtk] = S^T rows mtk*32..+31, cols q=ql
        f32x16 sc[2] = {};
        __builtin_amdgcn_s_setprio(1);
#pragma unroll
        for (int kd = 0; kd < 4; kd++)
#pragma unroll
            for (int mtk = 0; mtk < 2; mtk++) {
                int row = mtk * 32 + ql;
                bf16x8 af = *(const bf16x8*)&kb_[row * 64 + (((kd * 2 + hi) ^ (row & 7)) * 8)];
                sc[mtk] = __builtin_amdgcn_mfma_f32_32x32x16_bf16(af, aq[kd], sc[mtk], 0, 0, 0);
            }
        __builtin_amdgcn_s_setprio(0);

        // P = 2^(s + m*log2e); k_local = mtk*32 + (reg&3) + 8*(reg>>2) + 4*hi
#pragma unroll
        for (int mtk = 0; mtk < 2; mtk++)
#pragma unroll
            for (int g = 0; g < 4; g++) {
                f32x4 m4 = *(const f32x4*)&mlds[c * 64 + mtk * 32 + g * 8 + hi * 4];
#pragma unroll
                for (int j = 0; j < 4; j++) {
                    float p_ = __builtin_amdgcn_exp2f(sc[mtk][g * 4 + j] + m4[j]);
                    sc[mtk][g * 4 + j] = p_;
                    l_loc += p_;
                }
            }

        // pack + permlane32_swap -> P fragments (B-operand layout, k-steps 16)
        bf16x8 pa[4];
#pragma unroll
        for (int mtk = 0; mtk < 2; mtk++)
#pragma unroll
            for (int sub = 0; sub < 2; sub++) {
                unsigned a0, a1, b0, b1;
                __asm__("v_cvt_pk_bf16_f32 %0, %1, %2" : "=v"(a0)
                        : "v"(sc[mtk][sub * 8 + 0]), "v"(sc[mtk][sub * 8 + 1]));
                __asm__("v_cvt_pk_bf16_f32 %0, %1, %2" : "=v"(a1)
                        : "v"(sc[mtk][sub * 8 + 2]), "v"(sc[mtk][sub * 8 + 3]));
                __asm__("v_cvt_pk_bf16_f32 %0, %1, %2" : "=v"(b0)
                        : "v"(sc[mtk][sub * 8 + 4]), "v"(sc[mtk][sub * 8 + 5]));
                __asm__("v_cvt_pk_bf16_f32 %0, %1, %2" : "=v"(b1)
                        : "v"(sc[mtk][sub * 8 + 6]), "v"(sc[mtk][sub * 8 + 7]));
                __asm__("v_permlane32_swap_b32 %0, %1" : "+v"(a0), "+v"(b0));
                __asm__("v_permlane32_swap_b32 %0, %1" : "+v"(a1), "+v"(b1));
                union { unsigned u[4]; bf16x8 v; } fr;
                fr.u[0] = a0; fr.u[1] = a1; fr.u[2] = b0; fr.u[3] = b1;
                pa[mtk * 2 + sub] = fr.v;
            }

        // PV: O[ntd] += V^T(k-step) x P(k-step)   [A=V^T frag, B=pa]
        __builtin_amdgcn_s_setprio(1);
#pragma unroll
        for (int ks_ = 0; ks_ < 4; ks_++)
#pragma unroll
            for (int ntd = 0; ntd < 2; ntd++) {
                int row = ntd * 32 + ql;
                bf16x8 bvf = *(const bf16x8*)&vb_[row * 64 + (((ks_ * 2 + hi) ^ (row & 7)) * 8)];
                O[ntd] = __builtin_amdgcn_mfma_f32_32x32x16_bf16(bvf, pa[ks_], O[ntd], 0, 0, 0);
            }
        __builtin_amdgcn_s_setprio(0);

        slotC = (slotC == 2) ? 0 : slotC + 1;
        slotP = (slotP == 2) ? 0 : slotP + 1;
    }

    // l[q] = hi-half + lo-half partials
    l_loc += __shfl_xor(l_loc, 32, 64);

    // store: O D-layout col=q=ql, row=d = (reg&3)+8*(reg>>2)+4*hi (+ntd*32)
#pragma unroll
    for (int ntd = 0; ntd < 2; ntd++)
#pragma unroll
        for (int g = 0; g < 4; g++) {
            float4 o4;
            o4.x = O[ntd][g * 4 + 0] / l_loc;
            o4.y = O[ntd][g * 4 + 1] / l_loc;
            o4.z = O[ntd][g * 4 + 2] / l_loc;
            o4.w = O[ntd][g * 4 + 3] / l_loc;
            *(float4*)(out + (qrow0 + ql) * HDIM + h * HEAD_D + ntd * 32 + g * 8 + hi * 4) = o4;
        }
}

// ---------------- launch ----------------------------------------------------
extern "C" void kernel_launch(void* const* d_in, const int* in_sizes, int n_in,
                              void* d_out, int out_size, void* d_ws, size_t ws_size,
                              hipStream_t stream) {
    const float* hidden = (const float*)d_in[0];
    const float* mask   = (const float*)d_in[1];
    const int*   remain = (const int*)d_in[2];
    const float* Wq = (const float*)d_in[3];
    const float* bq = (const float*)d_in[4];
    const float* Wk = (const float*)d_in[5];
    const float* bk = (const float*)d_in[6];
    const float* Wv = (const float*)d_in[7];
    const float* bv = (const float*)d_in[8];
    float* out = (float*)d_out;

    // ws (~64.8MB): idx 16K | valid 16K | hbf 16.78M | wqb 2M | wkb 2M | wvb 2M
    //             | qp 8.39M | kp 16.78M | vt 16.78M     (wkb||wvb contiguous!)
    char* ws = (char*)d_ws;
    size_t off = 0;
    int* idx   = (int*)(ws + off); off += 16384;
    int* valid = (int*)(ws + off); off += 16384;
    ushort_t* hbf = (ushort_t*)(ws + off); off += (size_t)BATCH * S_LEN * HDIM * 2;
    ushort_t* wqb = (ushort_t*)(ws + off); off += (size_t)HDIM * HDIM * 2;
    ushort_t* wkb = (ushort_t*)(ws + off); off += (size_t)HDIM * HDIM * 2;
    ushort_t* wvb = (ushort_t*)(ws + off); off += (size_t)HDIM * HDIM * 2;
    ushort_t* qp  = (ushort_t*)(ws + off); off += (size_t)BATCH * KSEL * HDIM * 2;
    ushort_t* kp  = (ushort_t*)(ws + off); off += (size_t)BATCH * S_LEN * HDIM * 2;
    ushort_t* vt  = (ushort_t*)(ws + off); off += (size_t)BATCH * S_LEN * HDIM * 2;

    prep_kernel<<<2824, 1024, 0, stream>>>(hidden, Wq, Wk, Wv, remain,
                                           hbf, wqb, wkb, wvb, idx, valid);
    gemm_q<<<256, 256, 0, stream>>>(hbf, wqb, bq, idx, valid, qp);
    gemm_kv<<<512, 256, 0, stream>>>(hbf, wkb, bk, bv, kp, vt, 0);
    gemm_kv<<<512, 256, 0, stream>>>(hbf, wkb, bk, bv, kp, vt, 512);
    attn_kernel<<<512, 256, 0, stream>>>(qp, kp, vt, mask, out);
}

// Round 8
// 185.000 us; speedup vs baseline: 1.0689x; 1.0689x over previous
//
#include <hip/hip_runtime.h>
#include <hip/hip_bf16.h>
#include <stdint.h>

#define S_LEN 1024
#define HDIM  1024
#define NHEADS 16
#define HEAD_D 64
#define KSEL  512
#define BATCH 8

typedef unsigned short ushort_t;
typedef __attribute__((ext_vector_type(8))) __bf16 bf16x8;
typedef __attribute__((ext_vector_type(4))) float  f32x4;
typedef __attribute__((ext_vector_type(16))) float f32x16;

typedef const __attribute__((address_space(1))) void cg_void;
typedef __attribute__((address_space(3))) void lds_void;

__device__ __forceinline__ void gl_lds16(const void* g, void* l) {
    __builtin_amdgcn_global_load_lds((cg_void*)g, (lds_void*)l, 16, 0, 0);
}

// round-to-nearest-even f32 -> bf16 (finite inputs only)
__device__ __forceinline__ ushort_t f2bf(float f) {
    union { float f; unsigned int i; } x; x.f = f;
    unsigned int r = (x.i + 0x7fffu + ((x.i >> 16) & 1u)) >> 16;
    return (ushort_t)r;
}

#define BAR() __asm__ volatile("s_barrier" ::: "memory")
#define VMCNT(n) __asm__ volatile("s_waitcnt vmcnt(" #n ")" ::: "memory")
#define LGKM0() __asm__ volatile("s_waitcnt lgkmcnt(0)" ::: "memory")

// LEDGER (R7 discovery): the harness enqueues >=2 x 256MiB fillBuffer
// (~41us each, ~82us/iter) on the timed stream -- immovable overhead.
// Kernel budget: gemm ~60, attn ~28 (<40.8 hard bound), prep ~12.

// ---------------- kernel 0: prep = cvt(hidden,Wq,Wk,Wv) + compact -----------
__global__ __launch_bounds__(1024) void prep_kernel(
    const float* __restrict__ hidden, const float* __restrict__ wq,
    const float* __restrict__ wk, const float* __restrict__ wv,
    const int* __restrict__ remain,
    ushort_t* __restrict__ hbf, ushort_t* __restrict__ wqb,
    ushort_t* __restrict__ wkb, ushort_t* __restrict__ wvb,
    int* __restrict__ idx, int* __restrict__ valid) {
    __shared__ int wsum[16];
    __shared__ int woff[17];
    int blk = blockIdx.x;
    if (blk < 2816) {
        const float* s; ushort_t* d; int base;
        if (blk < 2048)      { s = hidden; d = hbf; base = blk; }
        else if (blk < 2304) { s = wq; d = wqb; base = blk - 2048; }
        else if (blk < 2560) { s = wk; d = wkb; base = blk - 2304; }
        else                 { s = wv; d = wvb; base = blk - 2560; }
        int i = base * 1024 + threadIdx.x;
        float4 v = ((const float4*)s)[i];
        ushort4 o;
        o.x = f2bf(v.x); o.y = f2bf(v.y); o.z = f2bf(v.z); o.w = f2bf(v.w);
        ((ushort4*)d)[i] = o;
    } else {
        int b = blk - 2816, t = threadIdx.x;
        int r = remain[b * S_LEN + t];
        unsigned long long m = __ballot(r != 0);
        int lane = t & 63, w = t >> 6;
        int pre = __popcll(m & ((1ull << lane) - 1ull));
        if (lane == 0) wsum[w] = __popcll(m);
        __syncthreads();
        if (t == 0) { int a = 0; for (int i = 0; i < 16; i++) { woff[i] = a; a += wsum[i]; } woff[16] = a; }
        __syncthreads();
        int tot = woff[16];
        int onesBefore = woff[w] + pre;
        int slot = r ? onesBefore : (tot + (t - onesBefore));
        if (slot < KSEL) { idx[b * KSEL + slot] = t; valid[b * KSEL + slot] = r; }
    }
}

// ---------------- kernel 1: fused K/V/Q projection GEMM (R6, verified 60us) -
// 128^2 tiles, BK=64, 4 blocks/CU; Q blocks first (LPT); per-XCD m-fastest
// order (B panel reused by 8 consecutive blocks; A slab L2-resident).
// R2/R3: 256^2 single-block-per-CU schedules LOSE (staging-concurrency).
#define QSCALE 0.1803368801111244f
#define LT_PITCH 136
__global__ __launch_bounds__(256, 4) void gemm_fused(
    const ushort_t* __restrict__ hbf, const ushort_t* __restrict__ wkv,
    const ushort_t* __restrict__ wq,
    const float* __restrict__ bk, const float* __restrict__ bv,
    const float* __restrict__ bq,
    const int* __restrict__ idx, const int* __restrict__ valid,
    ushort_t* __restrict__ kp, ushort_t* __restrict__ vt, ushort_t* __restrict__ qp) {
    __shared__ __align__(16) ushort_t pool[16384];   // 32 KB: As 8192 | Bs 8192
    ushort_t* As = pool;
    ushort_t* Bs = pool + 8192;
    const int i = blockIdx.x;
    int z, bmI, bnI;
    if (i < 256) { z = 1; bmI = i >> 3; bnI = i & 7; }
    else         { z = 0; int ii = i - 256; int x = ii & 7, j = ii >> 3;
                   bmI = x * 8 + (j & 7); bnI = j >> 3; }   // m fastest per XCD
    const long bm = (long)bmI * 128;
    const int bn = bnI * 128;

    const int tid = threadIdx.x;
    const int lane = tid & 63;
    const int w = tid >> 6;
    const int quad = lane >> 4;
    const int cl = lane & 15;
    const int srow = w * 16 + (lane >> 2);
    const int fs = ((lane >> 2) & 3) ^ ((lane >> 4) & 3);
    const int scol = ((lane & 3) ^ fs) * 8;
    const int lds_off = w * 512 + lane * 8;
    const int wr = (w >> 1) * 64, wc = (w & 1) * 64;
    const int fr = (cl & 3) ^ ((cl >> 2) & 3);
    const int qo = (quad ^ fr) * 8;

    const ushort_t* W = z ? wq : wkv;

    long ab[2];
#pragma unroll
    for (int p = 0; p < 2; p++) {
        long gr = bm + p * 64 + srow;
        if (z == 0) ab[p] = gr * HDIM;
        else {
            int b_ = (int)(gr >> 9);
            int src = idx[(b_ << 9) + ((int)gr & 511)];
            ab[p] = ((long)(b_ << 10) + src) * HDIM;
        }
    }

    f32x4 acc[4][4] = {};

    for (int k0 = 0; k0 < HDIM; k0 += 64) {
#pragma unroll
        for (int p = 0; p < 2; p++)
#pragma unroll
            for (int hh = 0; hh < 2; hh++) {
                gl_lds16(hbf + ab[p] + k0 + hh * 32 + scol, &As[hh * 4096 + p * 2048 + lds_off]);
                gl_lds16(W + ((long)(bn + p * 64 + srow)) * HDIM + k0 + hh * 32 + scol,
                         &Bs[hh * 4096 + p * 2048 + lds_off]);
            }
        __syncthreads();
#pragma unroll
        for (int hh = 0; hh < 2; hh++) {
            bf16x8 af[4], bfr[4];
#pragma unroll
            for (int mt = 0; mt < 4; mt++)
                af[mt] = *(const bf16x8*)&As[hh * 4096 + (wr + mt * 16 + cl) * 32 + qo];
#pragma unroll
            for (int nt = 0; nt < 4; nt++)
                bfr[nt] = *(const bf16x8*)&Bs[hh * 4096 + (wc + nt * 16 + cl) * 32 + qo];
#pragma unroll
            for (int mt = 0; mt < 4; mt++)
#pragma unroll
                for (int nt = 0; nt < 4; nt++)
                    acc[mt][nt] = __builtin_amdgcn_mfma_f32_16x16x32_bf16(af[mt], bfr[nt], acc[mt][nt], 0, 0, 0);
        }
        __syncthreads();
    }

    if (z == 1) {
#pragma unroll
        for (int nt = 0; nt < 4; nt++) {
            int col = bn + wc + nt * 16 + cl;
            float bvq = bq[col];
#pragma unroll
            for (int mt = 0; mt < 4; mt++) {
                long row = bm + wr + mt * 16 + quad * 4;
#pragma unroll
                for (int r = 0; r < 4; r++) {
                    float vm = (float)valid[row + r];
                    qp[(row + r) * HDIM + col] = f2bf((acc[mt][nt][r] * vm + bvq) * QSCALE);
                }
            }
        }
    } else if (bn < 1024) {
#pragma unroll
        for (int nt = 0; nt < 4; nt++) {
            int col = bn + wc + nt * 16 + cl;
            float bvk = bk[col];
#pragma unroll
            for (int mt = 0; mt < 4; mt++) {
                long row = bm + wr + mt * 16 + quad * 4;
#pragma unroll
                for (int r = 0; r < 4; r++)
                    kp[(row + r) * HDIM + col] = f2bf(acc[mt][nt][r] + bvk);
            }
        }
    } else {
        ushort_t* Lt = pool;
        long b_ = bm >> 10, s0 = bm & 1023;
#pragma unroll
        for (int p2 = 0; p2 < 2; p2++) {
            if ((w & 1) == p2) {
#pragma unroll
                for (int nt = 0; nt < 4; nt++) {
                    int cloc = nt * 16 + cl;
                    float bvv = bv[bn - 1024 + p2 * 64 + cloc];
#pragma unroll
                    for (int mt = 0; mt < 4; mt++) {
                        int row0 = wr + mt * 16 + quad * 4;
#pragma unroll
                        for (int r = 0; r < 4; r++)
                            Lt[cloc * LT_PITCH + row0 + r] = f2bf(acc[mt][nt][r] + bvv);
                    }
                }
            }
            __syncthreads();
            int c2 = tid >> 2, quarter = tid & 3;
            long gbase = ((b_ << 10) + (bn - 1024) + p2 * 64 + c2) * 1024 + s0 + quarter * 32;
            const ushort_t* src = Lt + c2 * LT_PITCH + quarter * 32;
#pragma unroll
            for (int q8 = 0; q8 < 4; q8++)
                *(bf16x8*)(vt + gbase + q8 * 8) = *(const bf16x8*)(src + q8 * 8);
            __syncthreads();
        }
    }
}

// ---------------- kernel 2: flash attention, swapped-QK^T + ring-3 ----------
// R7's XCD-grouped flat grid (kept; R8-vs-R6 isolates this one change):
// bid = xcd + 8*(qt + 4*g2), xcd = (h+16b)&7, g2 = (h+16b)>>3.  qt-siblings
// sharing one (b,h)'s 256KB K/V co-locate on one XCD; per-XCD K/V working
// set = 4MB = L2.  Ring-3 K/V staging + counted vmcnt (R6, verified).
__global__ __launch_bounds__(256, 2) void attn_kernel(
    const ushort_t* __restrict__ qp, const ushort_t* __restrict__ kp,
    const ushort_t* __restrict__ vt, const float* __restrict__ mask,
    float* __restrict__ out) {
    __shared__ __align__(16) ushort_t ks[3][4096];       // [slot][s(64)][d(64)]
    __shared__ __align__(16) ushort_t vs[3][4096];       // [slot][d(64)][s(64)]
    __shared__ float mlds[1024];
    const int tid = threadIdx.x;
    const int lane = tid & 63;
    const int w = tid >> 6;          // 0..3, 32 q-rows each
    const int ql = lane & 31;
    const int hi = lane >> 5;
    const int bid = blockIdx.x;
    const int xcd = bid & 7;
    const int slot = bid >> 3;
    const int qt = slot & 3;
    const int gg = xcd + 8 * (slot >> 2);
    const int h = gg & 15;
    const int b = gg >> 4;

    const int sr2 = tid >> 3;                         // 0..31
    const int scS = ((tid & 7) ^ (sr2 & 7)) * 8;      // elems, pre-swizzled src
    const int dOf = tid * 8;                          // dest elems per half

    const long kbase = (long)b * S_LEN;
    const long vbase = (long)b * 1024 + h * HEAD_D;

    // mask -> LDS, premultiplied by log2e
    {
        float4 mv4 = *(const float4*)(mask + b * S_LEN + tid * 4);
        mlds[tid * 4 + 0] = mv4.x * 1.44269504f;
        mlds[tid * 4 + 1] = mv4.y * 1.44269504f;
        mlds[tid * 4 + 2] = mv4.z * 1.44269504f;
        mlds[tid * 4 + 3] = mv4.w * 1.44269504f;
    }

    // Q as B-fragment: lane holds q = ql, d-elems kd*16 + hi*8 + j
    const long qrow0 = (long)b * KSEL + qt * 128 + w * 32;
    bf16x8 aq[4];
#pragma unroll
    for (int kd = 0; kd < 4; kd++)
        aq[kd] = *(const bf16x8*)(qp + (qrow0 + ql) * HDIM + h * HEAD_D + kd * 16 + hi * 8);

    f32x16 O[2] = {};
    float l_loc = 0.f;

    auto stage = [&](int t, int sl) {
#pragma unroll
        for (int j = 0; j < 2; j++) {
            gl_lds16(kp + (kbase + t * 64 + j * 32 + sr2) * (long)HDIM + h * HEAD_D + scS,
                     &ks[sl][j * 2048 + dOf]);
            gl_lds16(vt + (vbase + j * 32 + sr2) * (long)S_LEN + t * 64 + scS,
                     &vs[sl][j * 2048 + dOf]);
        }
    };

    // prologue: tiles 0,1 into slots 0,1
    stage(0, 0);
    stage(1, 1);
    LGKM0();                       // publish mlds before first barrier

    int slotC = 0;                 // c % 3
    int slotP = 2;                 // (c+2) % 3
    for (int c = 0; c < S_LEN / 64; c++) {
        BAR();                     // #1: all waves done reading tile c-1
        if (c + 2 < S_LEN / 64) stage(c + 2, slotP);
        if (c < 14)       { VMCNT(8); }
        else if (c == 14) { VMCNT(4); }
        else              { VMCNT(0); }
        BAR();                     // #2: stage(c) visible block-wide
        const ushort_t* kb_ = ks[slotC];
        const ushort_t* vb_ = vs[slotC];

        // QK^T (swapped): sc[mtk] = S^T rows mtk*32..+31, cols q=ql
        f32x16 sc[2] = {};
        __builtin_amdgcn_s_setprio(1);
#pragma unroll
        for (int kd = 0; kd < 4; kd++)
#pragma unroll
            for (int mtk = 0; mtk < 2; mtk++) {
                int row = mtk * 32 + ql;
                bf16x8 af = *(const bf16x8*)&kb_[row * 64 + (((kd * 2 + hi) ^ (row & 7)) * 8)];
                sc[mtk] = __builtin_amdgcn_mfma_f32_32x32x16_bf16(af, aq[kd], sc[mtk], 0, 0, 0);
            }
        __builtin_amdgcn_s_setprio(0);

        // P = 2^(s + m*log2e); k_local = mtk*32 + (reg&3) + 8*(reg>>2) + 4*hi
#pragma unroll
        for (int mtk = 0; mtk < 2; mtk++)
#pragma unroll
            for (int g = 0; g < 4; g++) {
                f32x4 m4 = *(const f32x4*)&mlds[c * 64 + mtk * 32 + g * 8 + hi * 4];
#pragma unroll
                for (int j = 0; j < 4; j++) {
                    float p_ = __builtin_amdgcn_exp2f(sc[mtk][g * 4 + j] + m4[j]);
                    sc[mtk][g * 4 + j] = p_;
                    l_loc += p_;
                }
            }

        // pack + permlane32_swap -> P fragments (B-operand layout, k-steps 16)
        bf16x8 pa[4];
#pragma unroll
        for (int mtk = 0; mtk < 2; mtk++)
#pragma unroll
            for (int sub = 0; sub < 2; sub++) {
                unsigned a0, a1, b0, b1;
                __asm__("v_cvt_pk_bf16_f32 %0, %1, %2" : "=v"(a0)
                        : "v"(sc[mtk][sub * 8 + 0]), "v"(sc[mtk][sub * 8 + 1]));
                __asm__("v_cvt_pk_bf16_f32 %0, %1, %2" : "=v"(a1)
                        : "v"(sc[mtk][sub * 8 + 2]), "v"(sc[mtk][sub * 8 + 3]));
                __asm__("v_cvt_pk_bf16_f32 %0, %1, %2" : "=v"(b0)
                        : "v"(sc[mtk][sub * 8 + 4]), "v"(sc[mtk][sub * 8 + 5]));
                __asm__("v_cvt_pk_bf16_f32 %0, %1, %2" : "=v"(b1)
                        : "v"(sc[mtk][sub * 8 + 6]), "v"(sc[mtk][sub * 8 + 7]));
                __asm__("v_permlane32_swap_b32 %0, %1" : "+v"(a0), "+v"(b0));
                __asm__("v_permlane32_swap_b32 %0, %1" : "+v"(a1), "+v"(b1));
                union { unsigned u[4]; bf16x8 v; } fr;
                fr.u[0] = a0; fr.u[1] = a1; fr.u[2] = b0; fr.u[3] = b1;
                pa[mtk * 2 + sub] = fr.v;
            }

        // PV: O[ntd] += V^T(k-step) x P(k-step)   [A=V^T frag, B=pa]
        __builtin_amdgcn_s_setprio(1);
#pragma unroll
        for (int ks_ = 0; ks_ < 4; ks_++)
#pragma unroll
            for (int ntd = 0; ntd < 2; ntd++) {
                int row = ntd * 32 + ql;
                bf16x8 bvf = *(const bf16x8*)&vb_[row * 64 + (((ks_ * 2 + hi) ^ (row & 7)) * 8)];
                O[ntd] = __builtin_amdgcn_mfma_f32_32x32x16_bf16(bvf, pa[ks_], O[ntd], 0, 0, 0);
            }
        __builtin_amdgcn_s_setprio(0);

        slotC = (slotC == 2) ? 0 : slotC + 1;
        slotP = (slotP == 2) ? 0 : slotP + 1;
    }

    // l[q] = hi-half + lo-half partials
    l_loc += __shfl_xor(l_loc, 32, 64);

    // store: O D-layout col=q=ql, row=d = (reg&3)+8*(reg>>2)+4*hi (+ntd*32)
#pragma unroll
    for (int ntd = 0; ntd < 2; ntd++)
#pragma unroll
        for (int g = 0; g < 4; g++) {
            float4 o4;
            o4.x = O[ntd][g * 4 + 0] / l_loc;
            o4.y = O[ntd][g * 4 + 1] / l_loc;
            o4.z = O[ntd][g * 4 + 2] / l_loc;
            o4.w = O[ntd][g * 4 + 3] / l_loc;
            *(float4*)(out + (qrow0 + ql) * HDIM + h * HEAD_D + ntd * 32 + g * 8 + hi * 4) = o4;
        }
}

// ---------------- launch ----------------------------------------------------
extern "C" void kernel_launch(void* const* d_in, const int* in_sizes, int n_in,
                              void* d_out, int out_size, void* d_ws, size_t ws_size,
                              hipStream_t stream) {
    const float* hidden = (const float*)d_in[0];
    const float* mask   = (const float*)d_in[1];
    const int*   remain = (const int*)d_in[2];
    const float* Wq = (const float*)d_in[3];
    const float* bq = (const float*)d_in[4];
    const float* Wk = (const float*)d_in[5];
    const float* bk = (const float*)d_in[6];
    const float* Wv = (const float*)d_in[7];
    const float* bv = (const float*)d_in[8];
    float* out = (float*)d_out;

    // ws (~64.8MB): idx 16K | valid 16K | hbf 16.78M | wqb 2M | wkb 2M | wvb 2M
    //             | qp 8.39M | kp 16.78M | vt 16.78M     (wkb||wvb contiguous!)
    char* ws = (char*)d_ws;
    size_t off = 0;
    int* idx   = (int*)(ws + off); off += 16384;
    int* valid = (int*)(ws + off); off += 16384;
    ushort_t* hbf = (ushort_t*)(ws + off); off += (size_t)BATCH * S_LEN * HDIM * 2;
    ushort_t* wqb = (ushort_t*)(ws + off); off += (size_t)HDIM * HDIM * 2;
    ushort_t* wkb = (ushort_t*)(ws + off); off += (size_t)HDIM * HDIM * 2;
    ushort_t* wvb = (ushort_t*)(ws + off); off += (size_t)HDIM * HDIM * 2;
    ushort_t* qp  = (ushort_t*)(ws + off); off += (size_t)BATCH * KSEL * HDIM * 2;
    ushort_t* kp  = (ushort_t*)(ws + off); off += (size_t)BATCH * S_LEN * HDIM * 2;
    ushort_t* vt  = (ushort_t*)(ws + off); off += (size_t)BATCH * S_LEN * HDIM * 2;

    prep_kernel<<<2824, 1024, 0, stream>>>(hidden, Wq, Wk, Wv, remain,
                                           hbf, wqb, wkb, wvb, idx, valid);
    gemm_fused<<<1280, 256, 0, stream>>>(hbf, wkb, wqb, bk, bv, bq,
                                         idx, valid, kp, vt, qp);
    attn_kernel<<<512, 256, 0, stream>>>(qp, kp, vt, mask, out);
}